// Round 1
// baseline (232.451 us; speedup 1.0000x reference)
//
#include <hip/hip_runtime.h>
#include <math.h>

#define RR 8
#define MM 1000000

// ---- prep: softmax(alpha_logits) -> w (in d_ws), sum(slack_params) -> slack_out
__global__ void prep_kernel(const float* __restrict__ alpha_logits,
                            const float* __restrict__ slack_params,
                            float* __restrict__ w_out,
                            float* __restrict__ slack_out) {
    if (threadIdx.x == 0 && blockIdx.x == 0) {
        float a[RR];
        float m = -INFINITY;
        #pragma unroll
        for (int r = 0; r < RR; ++r) { a[r] = alpha_logits[r]; m = fmaxf(m, a[r]); }
        float s = 0.f;
        #pragma unroll
        for (int r = 0; r < RR; ++r) { a[r] = expf(a[r] - m); s += a[r]; }
        float inv = 1.0f / s;
        float ss = 0.f;
        #pragma unroll
        for (int r = 0; r < RR; ++r) { w_out[r] = a[r] * inv; ss += slack_params[r]; }
        *slack_out = ss;
    }
}

// ---- main: per-b gather + weighted sum
__global__ __launch_bounds__(256) void meta_pred_kernel(
    const int* __restrict__ x,
    const float* __restrict__ mat,
    const float* __restrict__ rule_tables,
    const float* __restrict__ w_vec,
    float* __restrict__ out,
    int B) {
    int b = blockIdx.x * blockDim.x + threadIdx.x;
    if (b >= B) return;

    // uniform broadcast weights (L1-hot)
    float4 wlo = *reinterpret_cast<const float4*>(w_vec);
    float4 whi = *reinterpret_cast<const float4*>(w_vec + 4);
    float w[RR] = {wlo.x, wlo.y, wlo.z, wlo.w, whi.x, whi.y, whi.z, whi.w};

    long long row = (long long)x[b];
    const float4* mp = reinterpret_cast<const float4*>(mat + row * RR);
    float4 v0 = mp[0];
    float4 v1 = mp[1];
    float vals[RR] = {v0.x, v0.y, v0.z, v0.w, v1.x, v1.y, v1.z, v1.w};

    // compute all addresses / validity first so the 8 gathers issue back-to-back
    bool  valid[RR];
    int   idx[RR];
    #pragma unroll
    for (int r = 0; r < RR; ++r) {
        float v = vals[r];
        valid[r] = !(v != v);           // !isnan
        idx[r]   = valid[r] ? (int)v : 0;
    }

    float g[RR];
    #pragma unroll
    for (int r = 0; r < RR; ++r) {
        g[r] = rule_tables[(size_t)r * MM + (size_t)idx[r]];
    }

    float acc = 0.f;
    #pragma unroll
    for (int r = 0; r < RR; ++r) {
        acc += valid[r] ? g[r] * w[r] : 0.f;
    }
    out[b] = acc;
}

extern "C" void kernel_launch(void* const* d_in, const int* in_sizes, int n_in,
                              void* d_out, int out_size, void* d_ws, size_t ws_size,
                              hipStream_t stream) {
    const int*   x            = (const int*)d_in[0];
    const float* mat          = (const float*)d_in[1];
    const float* rule_tables  = (const float*)d_in[2];
    const float* alpha_logits = (const float*)d_in[3];
    const float* slack_params = (const float*)d_in[4];

    const int B = in_sizes[0];           // 2,000,000
    float* out   = (float*)d_out;        // [B] ret, then [1] slacks
    float* w_vec = (float*)d_ws;         // 8 floats scratch

    prep_kernel<<<1, 64, 0, stream>>>(alpha_logits, slack_params, w_vec, out + B);

    int block = 256;
    int grid  = (B + block - 1) / block;
    meta_pred_kernel<<<grid, block, 0, stream>>>(x, mat, rule_tables, w_vec, out, B);
}

// Round 3
// 137.991 us; speedup vs baseline: 1.6845x; 1.6845x over previous
//
#include <hip/hip_runtime.h>
#include <math.h>

#define RR 8
#define MM 1000000

typedef float f32x4 __attribute__((ext_vector_type(4)));
typedef int   i32x4 __attribute__((ext_vector_type(4)));

// ---- prep: softmax(alpha_logits) -> w (in d_ws), sum(slack_params) -> slack_out
__global__ void prep_kernel(const float* __restrict__ alpha_logits,
                            const float* __restrict__ slack_params,
                            float* __restrict__ w_out,
                            float* __restrict__ slack_out) {
    if (threadIdx.x == 0 && blockIdx.x == 0) {
        float a[RR];
        float m = -INFINITY;
        #pragma unroll
        for (int r = 0; r < RR; ++r) { a[r] = alpha_logits[r]; m = fmaxf(m, a[r]); }
        float s = 0.f;
        #pragma unroll
        for (int r = 0; r < RR; ++r) { a[r] = expf(a[r] - m); s += a[r]; }
        float inv = 1.0f / s;
        float ss = 0.f;
        #pragma unroll
        for (int r = 0; r < RR; ++r) { w_out[r] = a[r] * inv; ss += slack_params[r]; }
        *slack_out = ss;
    }
}

// ---- P1: gather mat rows, emit per-rule index planes tmp[r][b] (-1 = NaN)
__global__ __launch_bounds__(256) void gather_mat_kernel(
    const int* __restrict__ x,
    const float* __restrict__ mat,
    int* __restrict__ tmp, int B) {
    int b = blockIdx.x * 256 + threadIdx.x;
    if (b >= B) return;
    long long row = (long long)x[b];
    const f32x4* mp = reinterpret_cast<const f32x4*>(mat + row * RR);
    f32x4 v0 = mp[0];
    f32x4 v1 = mp[1];
    float vals[RR] = {v0.x, v0.y, v0.z, v0.w, v1.x, v1.y, v1.z, v1.w};
    #pragma unroll
    for (int r = 0; r < RR; ++r) {
        float v = vals[r];
        int idx = (v != v) ? -1 : (int)v;     // NaN -> -1
        __builtin_nontemporal_store(idx, tmp + (size_t)r * B + b);
    }
}

// ---- P2: per-rule table gather with rule<->XCD affinity (rule = blockIdx % 8)
__global__ __launch_bounds__(256) void rule_gather_kernel(
    const int* __restrict__ tmp,
    const float* __restrict__ rule_tables,
    const float* __restrict__ w_vec,
    float* __restrict__ partial, int B) {
    int rule  = blockIdx.x & 7;
    int chunk = blockIdx.x >> 3;
    int Nv = B >> 2;                          // float4 groups
    int t = chunk * 256 + threadIdx.x;
    const int*   tp  = tmp + (size_t)rule * B;
    const float* tab = rule_tables + (size_t)rule * MM;
    float*       pp  = partial + (size_t)rule * B;
    float w = w_vec[rule];
    if (t < Nv) {
        i32x4 iv = __builtin_nontemporal_load(reinterpret_cast<const i32x4*>(tp) + t);
        // issue all 4 gathers before the muls so they overlap
        float g0 = tab[iv.x >= 0 ? iv.x : 0];
        float g1 = tab[iv.y >= 0 ? iv.y : 0];
        float g2 = tab[iv.z >= 0 ? iv.z : 0];
        float g3 = tab[iv.w >= 0 ? iv.w : 0];
        f32x4 o;
        o.x = iv.x >= 0 ? g0 * w : 0.f;
        o.y = iv.y >= 0 ? g1 * w : 0.f;
        o.z = iv.z >= 0 ? g2 * w : 0.f;
        o.w = iv.w >= 0 ? g3 * w : 0.f;
        __builtin_nontemporal_store(o, reinterpret_cast<f32x4*>(pp) + t);
    } else if (t == Nv) {                     // tail (B % 4 != 0)
        for (int b = Nv * 4; b < B; ++b) {
            int i = tp[b];
            pp[b] = (i >= 0) ? tab[i] * w : 0.f;
        }
    }
}

// ---- P3: sum the 8 partial planes -> out
__global__ __launch_bounds__(256) void reduce_kernel(
    const float* __restrict__ partial,
    float* __restrict__ out, int B) {
    int Nv = B >> 2;
    int t = blockIdx.x * 256 + threadIdx.x;
    if (t < Nv) {
        f32x4 acc = {0.f, 0.f, 0.f, 0.f};
        #pragma unroll
        for (int r = 0; r < RR; ++r) {
            f32x4 v = __builtin_nontemporal_load(
                reinterpret_cast<const f32x4*>(partial + (size_t)r * B) + t);
            acc += v;
        }
        __builtin_nontemporal_store(acc, reinterpret_cast<f32x4*>(out) + t);
    } else if (t == Nv) {
        for (int b = Nv * 4; b < B; ++b) {
            float a = 0.f;
            for (int r = 0; r < RR; ++r) a += partial[(size_t)r * B + b];
            out[b] = a;
        }
    }
}

// ---- fallback single-pass kernel (round-1, used if ws too small)
__global__ __launch_bounds__(256) void meta_pred_kernel(
    const int* __restrict__ x,
    const float* __restrict__ mat,
    const float* __restrict__ rule_tables,
    const float* __restrict__ w_vec,
    float* __restrict__ out, int B) {
    int b = blockIdx.x * blockDim.x + threadIdx.x;
    if (b >= B) return;
    f32x4 wlo = *reinterpret_cast<const f32x4*>(w_vec);
    f32x4 whi = *reinterpret_cast<const f32x4*>(w_vec + 4);
    float w[RR] = {wlo.x, wlo.y, wlo.z, wlo.w, whi.x, whi.y, whi.z, whi.w};
    long long row = (long long)x[b];
    const f32x4* mp = reinterpret_cast<const f32x4*>(mat + row * RR);
    f32x4 v0 = mp[0];
    f32x4 v1 = mp[1];
    float vals[RR] = {v0.x, v0.y, v0.z, v0.w, v1.x, v1.y, v1.z, v1.w};
    bool valid[RR]; int idx[RR];
    #pragma unroll
    for (int r = 0; r < RR; ++r) {
        float v = vals[r];
        valid[r] = !(v != v);
        idx[r] = valid[r] ? (int)v : 0;
    }
    float g[RR];
    #pragma unroll
    for (int r = 0; r < RR; ++r) g[r] = rule_tables[(size_t)r * MM + (size_t)idx[r]];
    float acc = 0.f;
    #pragma unroll
    for (int r = 0; r < RR; ++r) acc += valid[r] ? g[r] * w[r] : 0.f;
    out[b] = acc;
}

extern "C" void kernel_launch(void* const* d_in, const int* in_sizes, int n_in,
                              void* d_out, int out_size, void* d_ws, size_t ws_size,
                              hipStream_t stream) {
    const int*   x            = (const int*)d_in[0];
    const float* mat          = (const float*)d_in[1];
    const float* rule_tables  = (const float*)d_in[2];
    const float* alpha_logits = (const float*)d_in[3];
    const float* slack_params = (const float*)d_in[4];

    const int B = in_sizes[0];                // 2,000,000
    float* out   = (float*)d_out;             // [B] ret, then [1] slacks
    float* w_vec = (float*)d_ws;              // 8 floats at ws[0:32)

    prep_kernel<<<1, 64, 0, stream>>>(alpha_logits, slack_params, w_vec, out + B);

    size_t plane_bytes = (size_t)RR * (size_t)B * sizeof(int);
    size_t needed = 256 + 2 * plane_bytes;

    if (ws_size >= needed) {
        int*   tmp     = (int*)((char*)d_ws + 256);
        float* partial = (float*)((char*)d_ws + 256 + plane_bytes);

        int grid1 = (B + 255) / 256;
        gather_mat_kernel<<<grid1, 256, 0, stream>>>(x, mat, tmp, B);

        int Nv = B >> 2;
        int chunks2 = (Nv + 256) / 256;       // +1 slot for tail thread
        rule_gather_kernel<<<chunks2 * RR, 256, 0, stream>>>(tmp, rule_tables, w_vec, partial, B);

        int grid3 = (Nv + 256) / 256;
        reduce_kernel<<<grid3, 256, 0, stream>>>(partial, out, B);
    } else {
        int grid = (B + 255) / 256;
        meta_pred_kernel<<<grid, 256, 0, stream>>>(x, mat, rule_tables, w_vec, out, B);
    }
}